// Round 9
// baseline (1187.572 us; speedup 1.0000x reference)
//
#include <hip/hip_runtime.h>
#include <hip/hip_bf16.h>

// Encoder: L=6, D=512, H=8, HD=64, F=2048, V=32000, N=2, S=2048, NS=4096
// fp32 in/out. MFMA everywhere. Split-K(4) flash attention: 512-thr blocks
// (128 queries, 8 waves, 32 waves/CU), exp2 softmax, l via ones-column,
// scale folded into Q, V in permuted-key layout so P-stores are b64.
// GEMMs: global_load_lds staging; N=512 GEMMs split-K(2) with bf16 partials,
// combine+bias+resid+LN fused. ws tiers: 74.4 | 66 | 37.7 MB.

#define NS_TOK 4096
#define DMODEL 512
#define NHEAD 8
#define HDIM 64
#define FFDIM 2048
#define SEQ 2048
#define NB 2

typedef __hip_bfloat16 bf16;
typedef __attribute__((ext_vector_type(8))) short short8;
typedef __attribute__((ext_vector_type(4))) float floatx4;

__device__ __forceinline__ float bf2f(bf16 x) { return __bfloat162float(x); }
__device__ __forceinline__ bf16 f2bf(float x) { return __float2bfloat16(x); }
__device__ __forceinline__ short bfbits(float x) {
    bf16 h = __float2bfloat16(x);
    return *reinterpret_cast<short*>(&h);
}
__device__ __forceinline__ float2 bf2x2(unsigned int u) {
    float2 r;
    r.x = __uint_as_float(u << 16);
    r.y = __uint_as_float(u & 0xffff0000u);
    return r;
}
__device__ __forceinline__ void gl2lds16(const void* g, void* l) {
    __builtin_amdgcn_global_load_lds(
        (const __attribute__((address_space(1))) void*)g,
        (__attribute__((address_space(3))) void*)l, 16, 0, 0);
}

// ---------------- weight fp32 -> bf16 conversion ----------------
__global__ __launch_bounds__(256) void k_conv(const float* __restrict__ src,
                                              bf16* __restrict__ dst, int count) {
    int i = (blockIdx.x * 256 + threadIdx.x) * 8;
    if (i >= count) return;
    float4 f0 = *(const float4*)(src + i);
    float4 f1 = *(const float4*)(src + i + 4);
    short8 sv;
    sv[0] = bfbits(f0.x); sv[1] = bfbits(f0.y);
    sv[2] = bfbits(f0.z); sv[3] = bfbits(f0.w);
    sv[4] = bfbits(f1.x); sv[5] = bfbits(f1.y);
    sv[6] = bfbits(f1.z); sv[7] = bfbits(f1.w);
    *(short8*)(dst + i) = sv;
}

// ---------------- embed ----------------
__global__ __launch_bounds__(256) void k_embed(const int* __restrict__ src,
                                               const float* __restrict__ emb,
                                               float* __restrict__ h,
                                               bf16* __restrict__ hb) {
    int row = blockIdx.x;
    int t = threadIdx.x;
    int tok = src[row];
    const float* e = emb + (size_t)tok * DMODEL;
    float v0 = e[t] * 22.62741699796952f;
    float v1 = e[t + 256] * 22.62741699796952f;
    h[(size_t)row * DMODEL + t] = v0;
    h[(size_t)row * DMODEL + t + 256] = v1;
    hb[(size_t)row * DMODEL + t] = f2bf(v0);
    hb[(size_t)row * DMODEL + t + 256] = f2bf(v1);
}

// ---------------- QKV via MFMA; Q pre-scaled; V stored permuted [dim][perm-key] --
// Permutation within each 64-token block: pi(t) = (t&15)*4 + (t>>4).
// V computed with swapped operands (A=Wv rows=dims, B=X rows=tokens) so the
// MFMA output cols are lane-contiguous in permuted token space -> short4 stores.
__global__ __launch_bounds__(256) void k_qkv(const bf16* __restrict__ hb,
    const float* __restrict__ Wq, const float* __restrict__ bq,
    const float* __restrict__ Wk, const float* __restrict__ bk,
    const float* __restrict__ Wv, const float* __restrict__ bv,
    bf16* __restrict__ Qo, bf16* __restrict__ Ko, bf16* __restrict__ Vt) {
    __shared__ __align__(16) short Xs[64 * 72];
    __shared__ __align__(16) short Ws3[3][64 * 72];
    int t = threadIdx.x, lane = t & 63, w = t >> 6;
    int l15 = lane & 15, quad = lane >> 4;
    int tok0 = blockIdx.x * 64, hh = blockIdx.y;
    int n = tok0 >> 11, s0loc = tok0 & 2047;
    const float QSC = 0.044194173824159216f * 1.44269504088896341f;
    const float* Ws[3] = {Wq, Wk, Wv};

    #pragma unroll
    for (int i = 0; i < 2; ++i) {
        int idx = t + i * 256;
        int row = idx >> 3, g = idx & 7;
        *(uint4*)&Xs[row * 72 + g * 8] =
            *(const uint4*)(hb + (size_t)(tok0 + row) * DMODEL + hh * HDIM + g * 8);
    }
    #pragma unroll
    for (int tn = 0; tn < 3; ++tn)
        #pragma unroll
        for (int i = 0; i < 2; ++i) {
            int idx = t + i * 256;
            int row = idx >> 3, g = idx & 7;
            const float* srcp = Ws[tn] + row * HDIM + g * 8;
            float4 f0 = *(const float4*)srcp;
            float4 f1 = *(const float4*)(srcp + 4);
            short8 sv;
            sv[0] = bfbits(f0.x); sv[1] = bfbits(f0.y);
            sv[2] = bfbits(f0.z); sv[3] = bfbits(f0.w);
            sv[4] = bfbits(f1.x); sv[5] = bfbits(f1.y);
            sv[6] = bfbits(f1.z); sv[7] = bfbits(f1.w);
            *(short8*)&Ws3[tn][row * 72 + g * 8] = sv;
        }
    __syncthreads();
    short8 aq[2];
    aq[0] = *(short8*)&Xs[(w * 16 + l15) * 72 + quad * 8];
    aq[1] = *(short8*)&Xs[(w * 16 + l15) * 72 + 32 + quad * 8];

    // Q, K: A = tokens, B = W rows
    #pragma unroll
    for (int tn = 0; tn < 2; ++tn) {
        const float* Bs = (tn == 0) ? bq : bk;
        floatx4 acc[4];
        #pragma unroll
        for (int fj = 0; fj < 4; ++fj)
            #pragma unroll
            for (int r = 0; r < 4; ++r) acc[fj][r] = 0.f;
        #pragma unroll
        for (int ks = 0; ks < 2; ++ks)
            #pragma unroll
            for (int fj = 0; fj < 4; ++fj) {
                short8 bfrag = *(short8*)&Ws3[tn][(fj * 16 + l15) * 72 + ks * 32 + quad * 8];
                acc[fj] = __builtin_amdgcn_mfma_f32_16x16x32_bf16(aq[ks], bfrag, acc[fj], 0, 0, 0);
            }
        bf16* O = (tn == 0) ? Qo : Ko;
        float sc = (tn == 0) ? QSC : 1.f;
        #pragma unroll
        for (int fj = 0; fj < 4; ++fj) {
            int col = fj * 16 + l15;
            float bias = Bs[col];
            #pragma unroll
            for (int r = 0; r < 4; ++r) {
                int tok = tok0 + w * 16 + quad * 4 + r;
                O[(size_t)tok * DMODEL + hh * HDIM + col] = f2bf((acc[fj][r] + bias) * sc);
            }
        }
    }
    // V swapped: A = Wv rows (dims), B = tokens
    {
        short8 av[2];
        av[0] = *(short8*)&Ws3[2][(w * 16 + l15) * 72 + quad * 8];
        av[1] = *(short8*)&Ws3[2][(w * 16 + l15) * 72 + 32 + quad * 8];
        floatx4 acc[4];
        #pragma unroll
        for (int fj = 0; fj < 4; ++fj)
            #pragma unroll
            for (int r = 0; r < 4; ++r) acc[fj][r] = 0.f;
        #pragma unroll
        for (int ks = 0; ks < 2; ++ks)
            #pragma unroll
            for (int fj = 0; fj < 4; ++fj) {
                short8 bx = *(short8*)&Xs[(fj * 16 + l15) * 72 + ks * 32 + quad * 8];
                acc[fj] = __builtin_amdgcn_mfma_f32_16x16x32_bf16(av[ks], bx, acc[fj], 0, 0, 0);
            }
        #pragma unroll
        for (int r = 0; r < 4; ++r) {
            int e = w * 16 + quad * 4 + r;               // output dim
            float bias = bv[e];
            short4 pk;
            pk.x = bfbits(acc[0][r] + bias);
            pk.y = bfbits(acc[1][r] + bias);
            pk.z = bfbits(acc[2][r] + bias);
            pk.w = bfbits(acc[3][r] + bias);
            // tokens fj*16+l15 -> permuted positions l15*4 + fj (contiguous)
            *(short4*)(Vt + ((size_t)((n * NHEAD + hh) * HDIM + e)) * SEQ
                       + s0loc + l15 * 4) = pk;
        }
    }
}

// ---------------- MFMA flash attention: 512 thr / 128 queries / split-K ---------
// P slabs alias dead Q staging (wave w's slab == its own Q rows). V tile is in
// permuted key space; P stored permuted (b64); S/mask stay natural-key.
__global__ __launch_bounds__(512, 8) void k_attn(const bf16* __restrict__ Qb,
                                                 const bf16* __restrict__ Kb,
                                                 const bf16* __restrict__ Vt,
                                                 const int* __restrict__ mask,
                                                 bf16* __restrict__ PoA,
                                                 bf16* __restrict__ PoB,
                                                 float* __restrict__ Mm,
                                                 float* __restrict__ Ll,
                                                 int ns_l2) {
    __shared__ __align__(16) short QPs[128 * 72];  // Q staging, then 8 P slabs
    __shared__ __align__(16) short Ks[64 * 72];
    __shared__ __align__(16) short Vs[80 * 72];    // 0-63 V^T perm; 64 ones; 65-79 zero
    int t = threadIdx.x, lane = t & 63, w = t >> 6;
    int l15 = lane & 15, quad = lane >> 4;
    int q0 = blockIdx.x * 128, hh = blockIdx.y;
    int z = blockIdx.z;
    int n = z >> ns_l2, sp = z & ((1 << ns_l2) - 1);
    size_t tokbase = (size_t)n * SEQ;
    size_t vbase = ((size_t)(n * NHEAD + hh) * HDIM) * SEQ;

    #pragma unroll
    for (int i = 0; i < 2; ++i) {
        int idx = t + 512 * i;
        int row = idx >> 3, q = idx & 7;
        *(uint4*)&QPs[row * 72 + q * 8] =
            *(const uint4*)(Qb + (tokbase + q0 + row) * DMODEL + hh * HDIM + q * 8);
    }
    for (int j = t; j < 16 * 72; j += 512) Vs[64 * 72 + j] = 0;
    if (t < 64) Vs[64 * 72 + t] = (short)0x3F80;   // bf16 1.0 ones-row (dim 64)
    __syncthreads();
    short8 aq[2];
    aq[0] = *(short8*)&QPs[(w * 16 + l15) * 72 + quad * 8];
    aq[1] = *(short8*)&QPs[(w * 16 + l15) * 72 + 32 + quad * 8];

    floatx4 accO[5];
    float mold[4];
    #pragma unroll
    for (int fn = 0; fn < 5; ++fn)
        #pragma unroll
        for (int r = 0; r < 4; ++r) accO[fn][r] = 0.f;
    #pragma unroll
    for (int r = 0; r < 4; ++r) mold[r] = -1.0e38f;

    int kquota = SEQ >> ns_l2;
    int kbeg = sp * kquota, kend = kbeg + kquota;
    for (int k0 = kbeg; k0 < kend; k0 += 64) {
        __syncthreads();
        {   // stage K (natural) and V^T (permuted global -> straight copy)
            int row = t >> 3, q = t & 7;
            *(uint4*)&Ks[row * 72 + q * 8] =
                *(const uint4*)(Kb + (tokbase + k0 + row) * DMODEL + hh * HDIM + q * 8);
            *(uint4*)&Vs[row * 72 + q * 8] =
                *(const uint4*)(Vt + vbase + (size_t)row * SEQ + k0 + q * 8);
        }
        __syncthreads();
        floatx4 accS[4];
        #pragma unroll
        for (int fj = 0; fj < 4; ++fj)
            #pragma unroll
            for (int r = 0; r < 4; ++r) accS[fj][r] = 0.f;
        #pragma unroll
        for (int ks = 0; ks < 2; ++ks)
            #pragma unroll
            for (int fj = 0; fj < 4; ++fj) {
                short8 bk = *(short8*)&Ks[(fj * 16 + l15) * 72 + ks * 32 + quad * 8];
                accS[fj] = __builtin_amdgcn_mfma_f32_16x16x32_bf16(aq[ks], bk, accS[fj], 0, 0, 0);
            }
        #pragma unroll
        for (int fj = 0; fj < 4; ++fj) {
            int mk = mask[n * SEQ + k0 + fj * 16 + l15];
            #pragma unroll
            for (int r = 0; r < 4; ++r)
                accS[fj][r] = mk ? accS[fj][r] : -1.0e9f;
        }
        float al[4];
        short* Ps = &QPs[w * 1152];
        #pragma unroll
        for (int r = 0; r < 4; ++r) {
            float mx = fmaxf(fmaxf(accS[0][r], accS[1][r]), fmaxf(accS[2][r], accS[3][r]));
            mx = fmaxf(mx, __shfl_xor(mx, 1, 64));
            mx = fmaxf(mx, __shfl_xor(mx, 2, 64));
            mx = fmaxf(mx, __shfl_xor(mx, 4, 64));
            mx = fmaxf(mx, __shfl_xor(mx, 8, 64));
            float mn = fmaxf(mold[r], mx);
            al[r] = exp2f(mold[r] - mn);
            mold[r] = mn;
            short4 pk;
            pk.x = bfbits(exp2f(accS[0][r] - mn));
            pk.y = bfbits(exp2f(accS[1][r] - mn));
            pk.z = bfbits(exp2f(accS[2][r] - mn));
            pk.w = bfbits(exp2f(accS[3][r] - mn));
            // key fj*16+l15 -> permuted col l15*4+fj: contiguous b64 store
            *(short4*)&Ps[(quad * 4 + r) * 72 + l15 * 4] = pk;
        }
        #pragma unroll
        for (int fn = 0; fn < 5; ++fn)
            #pragma unroll
            for (int r = 0; r < 4; ++r) accO[fn][r] *= al[r];
        #pragma unroll
        for (int ks = 0; ks < 2; ++ks) {
            short8 ap = *(short8*)&Ps[l15 * 72 + ks * 32 + quad * 8];
            #pragma unroll
            for (int fn = 0; fn < 5; ++fn) {
                short8 bv = *(short8*)&Vs[(fn * 16 + l15) * 72 + ks * 32 + quad * 8];
                accO[fn] = __builtin_amdgcn_mfma_f32_16x16x32_bf16(ap, bv, accO[fn], 0, 0, 0);
            }
        }
    }
    bf16* Pob = (sp < 2) ? PoA : PoB;
    #pragma unroll
    for (int r = 0; r < 4; ++r) {
        float ls = __shfl(accO[4][r], lane & 48);
        int row = q0 + w * 16 + quad * 4 + r;
        size_t gtok = tokbase + row;
        bf16* dst = Pob + ((size_t)(sp & 1) * NS_TOK + gtok) * DMODEL + hh * HDIM;
        #pragma unroll
        for (int fn = 0; fn < 4; ++fn)
            dst[fn * 16 + l15] = f2bf(accO[fn][r]);
        if (l15 == 0) {
            Mm[((size_t)sp * NS_TOK + gtok) * NHEAD + hh] = mold[r];
            Ll[((size_t)sp * NS_TOK + gtok) * NHEAD + hh] = ls;
        }
    }
}

// ---------------- combine K-splits (2 or 4) ----------------
__global__ __launch_bounds__(256) void k_comb(const bf16* __restrict__ PoA,
    const bf16* __restrict__ PoB, const float* __restrict__ Mm,
    const float* __restrict__ Ll, bf16* __restrict__ Ab, int nsplit) {
    int tok = blockIdx.x * 4 + (threadIdx.x >> 6);
    int lane = threadIdx.x & 63;
    int hh = lane >> 3;
    float m = -1.0e38f;
    for (int s = 0; s < nsplit; ++s)
        m = fmaxf(m, Mm[((size_t)s * NS_TOK + tok) * NHEAD + hh]);
    float L = 0.f, wgt[4];
    for (int s = 0; s < nsplit; ++s) {
        wgt[s] = exp2f(Mm[((size_t)s * NS_TOK + tok) * NHEAD + hh] - m);
        L += Ll[((size_t)s * NS_TOK + tok) * NHEAD + hh] * wgt[s];
    }
    float inv = 1.f / L;
    float acc[8] = {0.f, 0.f, 0.f, 0.f, 0.f, 0.f, 0.f, 0.f};
    for (int s = 0; s < nsplit; ++s) {
        const bf16* basep = ((s < 2) ? PoA : PoB) +
                            ((size_t)(s & 1) * NS_TOK + tok) * DMODEL + lane * 8;
        uint4 u = *(const uint4*)basep;
        const unsigned int* p = (const unsigned int*)&u;
        #pragma unroll
        for (int j = 0; j < 4; ++j) {
            float2 f = bf2x2(p[j]);
            acc[j * 2]     += f.x * wgt[s];
            acc[j * 2 + 1] += f.y * wgt[s];
        }
    }
    bf16* dst = Ab + (size_t)tok * DMODEL + lane * 8;
    #pragma unroll
    for (int j = 0; j < 8; ++j) dst[j] = f2bf(acc[j] * inv);
}

// ---------------- fast MFMA GEMM (global_load_lds staging), direct epilogue -----
template<int MT, int NT, bool RELU>
__global__ __launch_bounds__(256) void k_gemm_f(const bf16* __restrict__ A,
    const bf16* __restrict__ W, const float* __restrict__ bias, int K, int N,
    const float* __restrict__ resid, float* __restrict__ outF, bf16* __restrict__ outB) {
    constexpr int FI = MT / 32;
    constexpr int FJ = NT / 32;
    __shared__ __align__(16) short As[MT * 32];
    __shared__ __align__(16) short Bs[NT * 32];
    int t = threadIdx.x, lane = t & 63, w = t >> 6;
    int m0 = blockIdx.x * MT, n0 = blockIdx.y * NT;
    int wrow = (w >> 1) * (MT / 2), wcol = (w & 1) * (NT / 2);
    int quad = lane >> 4, mrow = lane & 15;
    int lr = lane >> 2, lc = (lane & 3) * 8;
    floatx4 acc[FI][FJ];
    #pragma unroll
    for (int fi = 0; fi < FI; ++fi)
        #pragma unroll
        for (int fj = 0; fj < FJ; ++fj)
            #pragma unroll
            for (int r = 0; r < 4; ++r) acc[fi][fj][r] = 0.f;

    for (int k0 = 0; k0 < K; k0 += 32) {
        __syncthreads();
        #pragma unroll
        for (int i = 0; i < MT / 64; ++i) {
            int rbase = (i * 4 + w) * 16;
            gl2lds16(A + (size_t)(m0 + rbase + lr) * K + k0 + lc, &As[rbase * 32]);
        }
        #pragma unroll
        for (int i = 0; i < NT / 64; ++i) {
            int rbase = (i * 4 + w) * 16;
            gl2lds16(W + (size_t)(n0 + rbase + lr) * K + k0 + lc, &Bs[rbase * 32]);
        }
        __syncthreads();
        short8 af[FI], bfr[FJ];
        #pragma unroll
        for (int fi = 0; fi < FI; ++fi)
            af[fi] = *(short8*)&As[(wrow + fi * 16 + mrow) * 32 + quad * 8];
        #pragma unroll
        for (int fj = 0; fj < FJ; ++fj)
            bfr[fj] = *(short8*)&Bs[(wcol + fj * 16 + mrow) * 32 + quad * 8];
        #pragma unroll
        for (int fi = 0; fi < FI; ++fi)
            #pragma unroll
            for (int fj = 0; fj < FJ; ++fj)
                acc[fi][fj] = __builtin_amdgcn_mfma_f32_16x16x32_bf16(
                    af[fi], bfr[fj], acc[fi][fj], 0, 0, 0);
    }
    #pragma unroll
    for (int fi = 0; fi < FI; ++fi)
        #pragma unroll
        for (int fj = 0; fj < FJ; ++fj) {
            int col = n0 + wcol + fj * 16 + mrow;
            float bv = bias[col];
            #pragma unroll
            for (int r = 0; r < 4; ++r) {
                int row = m0 + wrow + fi * 16 + quad * 4 + r;
                float v = acc[fi][fj][r] + bv;
                if (RELU) {
                    outB[(size_t)row * N + col] = f2bf(fmaxf(v, 0.f));
                } else {
                    outF[(size_t)row * N + col] = v + resid[(size_t)row * N + col];
                }
            }
        }
}

// ---------------- fast MFMA GEMM, split-K(2), bf16 partials ----------------
template<int MT, int NT>
__global__ __launch_bounds__(256) void k_gemm_sk(const bf16* __restrict__ A,
    const bf16* __restrict__ W, int K, int N,
    bf16* __restrict__ out0, bf16* __restrict__ out1) {
    constexpr int FI = MT / 32;
    constexpr int FJ = NT / 32;
    __shared__ __align__(16) short As[MT * 32];
    __shared__ __align__(16) short Bs[NT * 32];
    int t = threadIdx.x, lane = t & 63, w = t >> 6;
    int m0 = blockIdx.x * MT, n0 = blockIdx.y * NT;
    int wrow = (w >> 1) * (MT / 2), wcol = (w & 1) * (NT / 2);
    int quad = lane >> 4, mrow = lane & 15;
    int lr = lane >> 2, lc = (lane & 3) * 8;
    floatx4 acc[FI][FJ];
    #pragma unroll
    for (int fi = 0; fi < FI; ++fi)
        #pragma unroll
        for (int fj = 0; fj < FJ; ++fj)
            #pragma unroll
            for (int r = 0; r < 4; ++r) acc[fi][fj][r] = 0.f;

    int kh = K >> 1;
    int kbeg = blockIdx.z * kh;
    for (int k0 = kbeg; k0 < kbeg + kh; k0 += 32) {
        __syncthreads();
        #pragma unroll
        for (int i = 0; i < MT / 64; ++i) {
            int rbase = (i * 4 + w) * 16;
            gl2lds16(A + (size_t)(m0 + rbase + lr) * K + k0 + lc, &As[rbase * 32]);
        }
        #pragma unroll
        for (int i = 0; i < NT / 64; ++i) {
            int rbase = (i * 4 + w) * 16;
            gl2lds16(W + (size_t)(n0 + rbase + lr) * K + k0 + lc, &Bs[rbase * 32]);
        }
        __syncthreads();
        short8 af[FI], bfr[FJ];
        #pragma unroll
        for (int fi = 0; fi < FI; ++fi)
            af[fi] = *(short8*)&As[(wrow + fi * 16 + mrow) * 32 + quad * 8];
        #pragma unroll
        for (int fj = 0; fj < FJ; ++fj)
            bfr[fj] = *(short8*)&Bs[(wcol + fj * 16 + mrow) * 32 + quad * 8];
        #pragma unroll
        for (int fi = 0; fi < FI; ++fi)
            #pragma unroll
            for (int fj = 0; fj < FJ; ++fj)
                acc[fi][fj] = __builtin_amdgcn_mfma_f32_16x16x32_bf16(
                    af[fi], bfr[fj], acc[fi][fj], 0, 0, 0);
    }
    bf16* out = blockIdx.z ? out1 : out0;
    #pragma unroll
    for (int fi = 0; fi < FI; ++fi)
        #pragma unroll
        for (int fj = 0; fj < FJ; ++fj) {
            int col = n0 + wcol + fj * 16 + mrow;
            #pragma unroll
            for (int r = 0; r < 4; ++r) {
                int row = m0 + wrow + fi * 16 + quad * 4 + r;
                out[(size_t)row * N + col] = f2bf(acc[fi][fj][r]);
            }
        }
}

// ---------------- slow fp32-weight GEMM (tier-0 fallback) ----------------
template<int MT, bool RELU>
__global__ __launch_bounds__(256) void k_gemm(const bf16* __restrict__ A,
    const float* __restrict__ Wf, const float* __restrict__ bias, int K, int N,
    const float* __restrict__ resid, float* __restrict__ outF, bf16* __restrict__ outB) {
    constexpr int FI = 4;
    constexpr int FJ = (MT == 128) ? 4 : 2;
    __shared__ short As[MT * 40];
    __shared__ short Bs[128 * 40];
    int t = threadIdx.x, lane = t & 63, w = t >> 6;
    int m0 = blockIdx.x * MT, n0 = blockIdx.y * 128;
    int wrow = (MT == 128) ? (w >> 1) * 64 : 0;
    int wcol = (MT == 128) ? (w & 1) * 64 : w * 32;
    int quad = lane >> 4, mrow = lane & 15;
    floatx4 acc[FI][FJ];
    #pragma unroll
    for (int fi = 0; fi < FI; ++fi)
        #pragma unroll
        for (int fj = 0; fj < FJ; ++fj)
            #pragma unroll
            for (int r = 0; r < 4; ++r) acc[fi][fj][r] = 0.f;
    for (int k0 = 0; k0 < K; k0 += 32) {
        __syncthreads();
        #pragma unroll
        for (int i = 0; i < MT / 64; ++i) {
            int idx = t + i * 256;
            int row = idx >> 2, q = idx & 3;
            uint4 u = *(const uint4*)(A + (size_t)(m0 + row) * K + k0 + q * 8);
            *(uint4*)&As[row * 40 + q * 8] = u;
        }
        #pragma unroll
        for (int i = 0; i < 2; ++i) {
            int idx = t + i * 256;
            int row = idx >> 2, q = idx & 3;
            const float* src = Wf + (size_t)(n0 + row) * K + k0 + q * 8;
            float4 f0 = *(const float4*)src;
            float4 f1 = *(const float4*)(src + 4);
            short8 sv;
            sv[0] = bfbits(f0.x); sv[1] = bfbits(f0.y);
            sv[2] = bfbits(f0.z); sv[3] = bfbits(f0.w);
            sv[4] = bfbits(f1.x); sv[5] = bfbits(f1.y);
            sv[6] = bfbits(f1.z); sv[7] = bfbits(f1.w);
            *(short8*)&Bs[row * 40 + q * 8] = sv;
        }
        __syncthreads();
        short8 af[FI], bfr[FJ];
        #pragma unroll
        for (int fi = 0; fi < FI; ++fi)
            af[fi] = *(short8*)&As[(wrow + fi * 16 + mrow) * 40 + quad * 8];
        #pragma unroll
        for (int fj = 0; fj < FJ; ++fj)
            bfr[fj] = *(short8*)&Bs[(wcol + fj * 16 + mrow) * 40 + quad * 8];
        #pragma unroll
        for (int fi = 0; fi < FI; ++fi)
            #pragma unroll
            for (int fj = 0; fj < FJ; ++fj)
                acc[fi][fj] = __builtin_amdgcn_mfma_f32_16x16x32_bf16(
                    af[fi], bfr[fj], acc[fi][fj], 0, 0, 0);
    }
    #pragma unroll
    for (int fi = 0; fi < FI; ++fi)
        #pragma unroll
        for (int fj = 0; fj < FJ; ++fj) {
            int col = n0 + wcol + fj * 16 + mrow;
            float bv = bias[col];
            #pragma unroll
            for (int r = 0; r < 4; ++r) {
                int row = m0 + wrow + fi * 16 + quad * 4 + r;
                float v = acc[fi][fj][r] + bv;
                if (RELU) {
                    outB[(size_t)row * N + col] = f2bf(fmaxf(v, 0.f));
                } else {
                    outF[(size_t)row * N + col] = v + resid[(size_t)row * N + col];
                }
            }
        }
}

// ---------------- LayerNorm (plain, tiers 0/1) ----------------
__global__ __launch_bounds__(256) void k_ln(const float* __restrict__ P,
    const float* __restrict__ g, const float* __restrict__ b,
    float* __restrict__ outF, bf16* __restrict__ outB) {
    int row = blockIdx.x * 4 + (threadIdx.x >> 6);
    int lane = threadIdx.x & 63;
    const float* p = P + (size_t)row * DMODEL + lane * 8;
    float4 a = *(const float4*)p;
    float4 c = *(const float4*)(p + 4);
    float s = a.x + a.y + a.z + a.w + c.x + c.y + c.z + c.w;
    #pragma unroll
    for (int off = 32; off > 0; off >>= 1) s += __shfl_xor(s, off, 64);
    float mean = s * (1.f / DMODEL);
    float d[8] = {a.x - mean, a.y - mean, a.z - mean, a.w - mean,
                  c.x - mean, c.y - mean, c.z - mean, c.w - mean};
    float vs = 0.f;
    #pragma unroll
    for (int j = 0; j < 8; ++j) vs += d[j] * d[j];
    #pragma unroll
    for (int off = 32; off > 0; off >>= 1) vs += __shfl_xor(vs, off, 64);
    float rstd = rsqrtf(vs * (1.f / DMODEL) + 1e-5f);
    float4 g0 = *(const float4*)(g + lane * 8);
    float4 g1 = *(const float4*)(g + lane * 8 + 4);
    float4 b0 = *(const float4*)(b + lane * 8);
    float4 b1 = *(const float4*)(b + lane * 8 + 4);
    float o[8] = {d[0] * rstd * g0.x + b0.x, d[1] * rstd * g0.y + b0.y,
                  d[2] * rstd * g0.z + b0.z, d[3] * rstd * g0.w + b0.w,
                  d[4] * rstd * g1.x + b1.x, d[5] * rstd * g1.y + b1.y,
                  d[6] * rstd * g1.z + b1.z, d[7] * rstd * g1.w + b1.w};
    float* of = outF + (size_t)row * DMODEL + lane * 8;
    *(float4*)of       = make_float4(o[0], o[1], o[2], o[3]);
    *(float4*)(of + 4) = make_float4(o[4], o[5], o[6], o[7]);
    if (outB) {
        bf16* ob = outB + (size_t)row * DMODEL + lane * 8;
        #pragma unroll
        for (int j = 0; j < 8; ++j) ob[j] = f2bf(o[j]);
    }
}

// ---------------- fused: combine bf16 split-K partials + bias + resid + LN ------
__global__ __launch_bounds__(256) void k_lncomb(const bf16* __restrict__ pp0,
    const bf16* __restrict__ pp1, const float* __restrict__ bias,
    const float* __restrict__ resid, const float* __restrict__ g,
    const float* __restrict__ b, float* __restrict__ outF, bf16* __restrict__ outB) {
    int row = blockIdx.x * 4 + (threadIdx.x >> 6);
    int lane = threadIdx.x & 63;
    size_t idx = (size_t)row * DMODEL + lane * 8;
    uint4 u0 = *(const uint4*)(pp0 + idx);
    uint4 u1 = *(const uint4*)(pp1 + idx);
    float4 r0 = *(const float4*)(resid + idx), r1 = *(const float4*)(resid + idx + 4);
    float4 q0 = *(const float4*)(bias + lane * 8), q1 = *(const float4*)(bias + lane * 8 + 4);
    const unsigned int* a0 = (const unsigned int*)&u0;
    const unsigned int* a1 = (const unsigned int*)&u1;
    float v[8];
    #pragma unroll
    for (int j = 0; j < 4; ++j) {
        float2 f0 = bf2x2(a0[j]), f1 = bf2x2(a1[j]);
        v[j * 2]     = f0.x + f1.x;
        v[j * 2 + 1] = f0.y + f1.y;
    }
    v[0] += r0.x + q0.x; v[1] += r0.y + q0.y; v[2] += r0.z + q0.z; v[3] += r0.w + q0.w;
    v[4] += r1.x + q1.x; v[5] += r1.y + q1.y; v[6] += r1.z + q1.z; v[7] += r1.w + q1.w;
    float s = 0.f;
    #pragma unroll
    for (int j = 0; j < 8; ++j) s += v[j];
    #pragma unroll
    for (int off = 32; off > 0; off >>= 1) s += __shfl_xor(s, off, 64);
    float mean = s * (1.f / DMODEL);
    float vs = 0.f;
    #pragma unroll
    for (int j = 0; j < 8; ++j) { v[j] -= mean; vs += v[j] * v[j]; }
    #pragma unroll
    for (int off = 32; off > 0; off >>= 1) vs += __shfl_xor(vs, off, 64);
    float rstd = rsqrtf(vs * (1.f / DMODEL) + 1e-5f);
    float4 g0 = *(const float4*)(g + lane * 8);
    float4 g1 = *(const float4*)(g + lane * 8 + 4);
    float4 b0 = *(const float4*)(b + lane * 8);
    float4 b1 = *(const float4*)(b + lane * 8 + 4);
    float o[8] = {v[0] * rstd * g0.x + b0.x, v[1] * rstd * g0.y + b0.y,
                  v[2] * rstd * g0.z + b0.z, v[3] * rstd * g0.w + b0.w,
                  v[4] * rstd * g1.x + b1.x, v[5] * rstd * g1.y + b1.y,
                  v[6] * rstd * g1.z + b1.z, v[7] * rstd * g1.w + b1.w};
    float* of = outF + idx;
    *(float4*)of       = make_float4(o[0], o[1], o[2], o[3]);
    *(float4*)(of + 4) = make_float4(o[4], o[5], o[6], o[7]);
    if (outB) {
        bf16* ob = outB + idx;
        #pragma unroll
        for (int j = 0; j < 8; ++j) ob[j] = f2bf(o[j]);
    }
}

extern "C" void kernel_launch(void* const* d_in, const int* in_sizes, int n_in,
                              void* d_out, int out_size, void* d_ws, size_t ws_size,
                              hipStream_t stream) {
    const int*   src  = (const int*)d_in[0];
    const int*   mask = (const int*)d_in[1];
    const float* emb  = (const float*)d_in[2];
    const float* Wq   = (const float*)d_in[3];
    const float* bq   = (const float*)d_in[4];
    const float* Wk   = (const float*)d_in[5];
    const float* bk   = (const float*)d_in[6];
    const float* Wv   = (const float*)d_in[7];
    const float* bv   = (const float*)d_in[8];
    const float* Wo   = (const float*)d_in[9];
    const float* bo   = (const float*)d_in[10];
    const float* W1   = (const float*)d_in[11];
    const float* b1   = (const float*)d_in[12];
    const float* W2   = (const float*)d_in[13];
    const float* b2   = (const float*)d_in[14];
    const float* ln1g = (const float*)d_in[15];
    const float* ln1b = (const float*)d_in[16];
    const float* ln2g = (const float*)d_in[17];
    const float* ln2b = (const float*)d_in[18];

    char* base = (char*)d_ws;
    float* h   = (float*)base;                       // 8,388,608
    float* hbf = (float*)(base + 8388608);           // 4,194,304 (hb + Mm/Ll alias)
    bf16*  hb  = (bf16*)hbf;
    float* Mm  = hbf;
    float* Ll  = hbf + 4 * NS_TOK * NHEAD;
    char*  P0r = base + 12582912;                    // 8,388,608
    bf16*  Qb  = (bf16*)(base + 20971520);           // 4 x 4,194,304
    bf16*  Kb  = (bf16*)(base + 25165824);
    bf16*  Vt  = (bf16*)(base + 29360128);           // permuted-key V [dim][key']
    bf16*  Ab  = (bf16*)(base + 33554432);
    bf16*  F1b = Qb;                                  // aliases Qb..Ab
    bf16*  Wob = (bf16*)(base + 37748736);           // 3,145,728
    bf16*  W1b = (bf16*)(base + 40894464);           // 12,582,912
    bf16*  W2b = (bf16*)(base + 53477376);           // 12,582,912
    char*  P1r = base + 66060288;                    // 8,388,608 -> 74,448,896
    int tier = (ws_size >= 74448896ull) ? 2 : ((ws_size >= 66060288ull) ? 1 : 0);

    if (tier >= 1) {
        k_conv<<<(6 * DMODEL * DMODEL) / 2048, 256, 0, stream>>>(Wo, Wob, 6 * DMODEL * DMODEL);
        k_conv<<<(6 * FFDIM * DMODEL) / 2048, 256, 0, stream>>>(W1, W1b, 6 * FFDIM * DMODEL);
        k_conv<<<(6 * FFDIM * DMODEL) / 2048, 256, 0, stream>>>(W2, W2b, 6 * FFDIM * DMODEL);
    }
    k_embed<<<NS_TOK, 256, 0, stream>>>(src, emb, h, hb);

    int ns_l2 = (tier == 2) ? 2 : 1;
    int nsplit = 1 << ns_l2;
    bf16* PoA = (bf16*)P0r;
    bf16* PoB = (tier == 2) ? (bf16*)P1r : (bf16*)P0r;
    bf16* Pp0 = (bf16*)P0r;
    bf16* Pp1 = (tier == 2) ? (bf16*)P1r : (bf16*)P0r;

    for (int l = 0; l < 6; ++l) {
        k_qkv<<<dim3(NS_TOK / 64, NHEAD), 256, 0, stream>>>(hb,
            Wq + (size_t)l * HDIM * HDIM, bq + l * HDIM,
            Wk + (size_t)l * HDIM * HDIM, bk + l * HDIM,
            Wv + (size_t)l * HDIM * HDIM, bv + l * HDIM,
            Qb, Kb, Vt);
        k_attn<<<dim3(SEQ / 128, NHEAD, NB * nsplit), 512, 0, stream>>>(
            Qb, Kb, Vt, mask, PoA, PoB, Mm, Ll, ns_l2);
        k_comb<<<NS_TOK / 4, 256, 0, stream>>>(PoA, PoB, Mm, Ll, Ab, nsplit);

        float* lnout = (l == 5) ? (float*)d_out : h;
        bf16* lnoutB = (l == 5) ? nullptr : hb;

        if (tier == 2) {
            k_gemm_sk<64, 128><<<dim3(NS_TOK / 64, DMODEL / 128, 2), 256, 0, stream>>>(
                Ab, Wob + (size_t)l * DMODEL * DMODEL, DMODEL, DMODEL, Pp0, Pp1);
            k_lncomb<<<NS_TOK / 4, 256, 0, stream>>>(Pp0, Pp1, bo + l * DMODEL, h,
                ln1g + l * DMODEL, ln1b + l * DMODEL, h, hb);
            k_gemm_f<128, 128, true><<<dim3(NS_TOK / 128, FFDIM / 128), 256, 0, stream>>>(
                hb, W1b + (size_t)l * FFDIM * DMODEL, b1 + l * FFDIM,
                DMODEL, FFDIM, nullptr, nullptr, F1b);
            k_gemm_sk<64, 128><<<dim3(NS_TOK / 64, DMODEL / 128, 2), 256, 0, stream>>>(
                F1b, W2b + (size_t)l * DMODEL * FFDIM, FFDIM, DMODEL, Pp0, Pp1);
            k_lncomb<<<NS_TOK / 4, 256, 0, stream>>>(Pp0, Pp1, b2 + l * DMODEL, h,
                ln2g + l * DMODEL, ln2b + l * DMODEL, lnout, lnoutB);
        } else if (tier == 1) {
            k_gemm_f<64, 128, false><<<dim3(NS_TOK / 64, DMODEL / 128), 256, 0, stream>>>(
                Ab, Wob + (size_t)l * DMODEL * DMODEL, bo + l * DMODEL,
                DMODEL, DMODEL, h, (float*)P0r, nullptr);
            k_ln<<<NS_TOK / 4, 256, 0, stream>>>((float*)P0r, ln1g + l * DMODEL, ln1b + l * DMODEL, h, hb);
            k_gemm_f<128, 128, true><<<dim3(NS_TOK / 128, FFDIM / 128), 256, 0, stream>>>(
                hb, W1b + (size_t)l * FFDIM * DMODEL, b1 + l * FFDIM,
                DMODEL, FFDIM, nullptr, nullptr, F1b);
            k_gemm_f<64, 128, false><<<dim3(NS_TOK / 64, DMODEL / 128), 256, 0, stream>>>(
                F1b, W2b + (size_t)l * DMODEL * FFDIM, b2 + l * DMODEL,
                FFDIM, DMODEL, h, (float*)P0r, nullptr);
            k_ln<<<NS_TOK / 4, 256, 0, stream>>>((float*)P0r, ln2g + l * DMODEL, ln2b + l * DMODEL, lnout, lnoutB);
        } else {
            k_gemm<64, false><<<dim3(NS_TOK / 64, DMODEL / 128), 256, 0, stream>>>(
                Ab, Wo + (size_t)l * DMODEL * DMODEL, bo + l * DMODEL,
                DMODEL, DMODEL, h, (float*)P0r, nullptr);
            k_ln<<<NS_TOK / 4, 256, 0, stream>>>((float*)P0r, ln1g + l * DMODEL, ln1b + l * DMODEL, h, hb);
            k_gemm<128, true><<<dim3(NS_TOK / 128, FFDIM / 128), 256, 0, stream>>>(
                hb, W1 + (size_t)l * FFDIM * DMODEL, b1 + l * FFDIM,
                DMODEL, FFDIM, nullptr, nullptr, F1b);
            k_gemm<64, false><<<dim3(NS_TOK / 64, DMODEL / 128), 256, 0, stream>>>(
                F1b, W2 + (size_t)l * DMODEL * FFDIM, b2 + l * DMODEL,
                FFDIM, DMODEL, h, (float*)P0r, nullptr);
            k_ln<<<NS_TOK / 4, 256, 0, stream>>>((float*)P0r, ln2g + l * DMODEL, ln2b + l * DMODEL, lnout, lnoutB);
        }
    }
}

// Round 10
// 968.783 us; speedup vs baseline: 1.2258x; 1.2258x over previous
//
#include <hip/hip_runtime.h>
#include <hip/hip_bf16.h>

// Encoder: L=6, D=512, H=8, HD=64, F=2048, V=32000, N=2, S=2048, NS=4096
// fp32 in/out. MFMA everywhere. Split-K(4) flash attention: 512-thr blocks
// (128 queries, 8 waves), launch_bounds(512,4) -- (512,8) forced 32-VGPR spills
// (round 9: 400 MB scratch traffic). exp2 softmax, l via ones-column, scale in Q,
// V permuted-key so P-stores are b64. GEMMs: global_load_lds; N=512 GEMMs
// split-K(2) bf16 partials + fused lncomb. ws tiers: 74.4 | 66 | 37.7 MB.

#define NS_TOK 4096
#define DMODEL 512
#define NHEAD 8
#define HDIM 64
#define FFDIM 2048
#define SEQ 2048
#define NB 2

typedef __hip_bfloat16 bf16;
typedef __attribute__((ext_vector_type(8))) short short8;
typedef __attribute__((ext_vector_type(4))) float floatx4;

__device__ __forceinline__ float bf2f(bf16 x) { return __bfloat162float(x); }
__device__ __forceinline__ bf16 f2bf(float x) { return __float2bfloat16(x); }
__device__ __forceinline__ short bfbits(float x) {
    bf16 h = __float2bfloat16(x);
    return *reinterpret_cast<short*>(&h);
}
__device__ __forceinline__ float2 bf2x2(unsigned int u) {
    float2 r;
    r.x = __uint_as_float(u << 16);
    r.y = __uint_as_float(u & 0xffff0000u);
    return r;
}
__device__ __forceinline__ void gl2lds16(const void* g, void* l) {
    __builtin_amdgcn_global_load_lds(
        (const __attribute__((address_space(1))) void*)g,
        (__attribute__((address_space(3))) void*)l, 16, 0, 0);
}

// ---------------- weight fp32 -> bf16 conversion ----------------
__global__ __launch_bounds__(256) void k_conv(const float* __restrict__ src,
                                              bf16* __restrict__ dst, int count) {
    int i = (blockIdx.x * 256 + threadIdx.x) * 8;
    if (i >= count) return;
    float4 f0 = *(const float4*)(src + i);
    float4 f1 = *(const float4*)(src + i + 4);
    short8 sv;
    sv[0] = bfbits(f0.x); sv[1] = bfbits(f0.y);
    sv[2] = bfbits(f0.z); sv[3] = bfbits(f0.w);
    sv[4] = bfbits(f1.x); sv[5] = bfbits(f1.y);
    sv[6] = bfbits(f1.z); sv[7] = bfbits(f1.w);
    *(short8*)(dst + i) = sv;
}

// ---------------- embed ----------------
__global__ __launch_bounds__(256) void k_embed(const int* __restrict__ src,
                                               const float* __restrict__ emb,
                                               float* __restrict__ h,
                                               bf16* __restrict__ hb) {
    int row = blockIdx.x;
    int t = threadIdx.x;
    int tok = src[row];
    const float* e = emb + (size_t)tok * DMODEL;
    float v0 = e[t] * 22.62741699796952f;
    float v1 = e[t + 256] * 22.62741699796952f;
    h[(size_t)row * DMODEL + t] = v0;
    h[(size_t)row * DMODEL + t + 256] = v1;
    hb[(size_t)row * DMODEL + t] = f2bf(v0);
    hb[(size_t)row * DMODEL + t + 256] = f2bf(v1);
}

// ---------------- QKV via MFMA; Q pre-scaled; V stored permuted [dim][perm-key] --
__global__ __launch_bounds__(256) void k_qkv(const bf16* __restrict__ hb,
    const float* __restrict__ Wq, const float* __restrict__ bq,
    const float* __restrict__ Wk, const float* __restrict__ bk,
    const float* __restrict__ Wv, const float* __restrict__ bv,
    bf16* __restrict__ Qo, bf16* __restrict__ Ko, bf16* __restrict__ Vt) {
    __shared__ __align__(16) short Xs[64 * 72];
    __shared__ __align__(16) short Ws3[3][64 * 72];
    int t = threadIdx.x, lane = t & 63, w = t >> 6;
    int l15 = lane & 15, quad = lane >> 4;
    int tok0 = blockIdx.x * 64, hh = blockIdx.y;
    int n = tok0 >> 11, s0loc = tok0 & 2047;
    const float QSC = 0.044194173824159216f * 1.44269504088896341f;
    const float* Ws[3] = {Wq, Wk, Wv};

    #pragma unroll
    for (int i = 0; i < 2; ++i) {
        int idx = t + i * 256;
        int row = idx >> 3, g = idx & 7;
        *(uint4*)&Xs[row * 72 + g * 8] =
            *(const uint4*)(hb + (size_t)(tok0 + row) * DMODEL + hh * HDIM + g * 8);
    }
    #pragma unroll
    for (int tn = 0; tn < 3; ++tn)
        #pragma unroll
        for (int i = 0; i < 2; ++i) {
            int idx = t + i * 256;
            int row = idx >> 3, g = idx & 7;
            const float* srcp = Ws[tn] + row * HDIM + g * 8;
            float4 f0 = *(const float4*)srcp;
            float4 f1 = *(const float4*)(srcp + 4);
            short8 sv;
            sv[0] = bfbits(f0.x); sv[1] = bfbits(f0.y);
            sv[2] = bfbits(f0.z); sv[3] = bfbits(f0.w);
            sv[4] = bfbits(f1.x); sv[5] = bfbits(f1.y);
            sv[6] = bfbits(f1.z); sv[7] = bfbits(f1.w);
            *(short8*)&Ws3[tn][row * 72 + g * 8] = sv;
        }
    __syncthreads();
    short8 aq[2];
    aq[0] = *(short8*)&Xs[(w * 16 + l15) * 72 + quad * 8];
    aq[1] = *(short8*)&Xs[(w * 16 + l15) * 72 + 32 + quad * 8];

    // Q, K: A = tokens, B = W rows
    #pragma unroll
    for (int tn = 0; tn < 2; ++tn) {
        const float* Bs = (tn == 0) ? bq : bk;
        floatx4 acc[4];
        #pragma unroll
        for (int fj = 0; fj < 4; ++fj)
            #pragma unroll
            for (int r = 0; r < 4; ++r) acc[fj][r] = 0.f;
        #pragma unroll
        for (int ks = 0; ks < 2; ++ks)
            #pragma unroll
            for (int fj = 0; fj < 4; ++fj) {
                short8 bfrag = *(short8*)&Ws3[tn][(fj * 16 + l15) * 72 + ks * 32 + quad * 8];
                acc[fj] = __builtin_amdgcn_mfma_f32_16x16x32_bf16(aq[ks], bfrag, acc[fj], 0, 0, 0);
            }
        bf16* O = (tn == 0) ? Qo : Ko;
        float sc = (tn == 0) ? QSC : 1.f;
        #pragma unroll
        for (int fj = 0; fj < 4; ++fj) {
            int col = fj * 16 + l15;
            float bias = Bs[col];
            #pragma unroll
            for (int r = 0; r < 4; ++r) {
                int tok = tok0 + w * 16 + quad * 4 + r;
                O[(size_t)tok * DMODEL + hh * HDIM + col] = f2bf((acc[fj][r] + bias) * sc);
            }
        }
    }
    // V swapped: A = Wv rows (dims), B = tokens -> permuted-token cols
    {
        short8 av[2];
        av[0] = *(short8*)&Ws3[2][(w * 16 + l15) * 72 + quad * 8];
        av[1] = *(short8*)&Ws3[2][(w * 16 + l15) * 72 + 32 + quad * 8];
        floatx4 acc[4];
        #pragma unroll
        for (int fj = 0; fj < 4; ++fj)
            #pragma unroll
            for (int r = 0; r < 4; ++r) acc[fj][r] = 0.f;
        #pragma unroll
        for (int ks = 0; ks < 2; ++ks)
            #pragma unroll
            for (int fj = 0; fj < 4; ++fj) {
                short8 bx = *(short8*)&Xs[(fj * 16 + l15) * 72 + ks * 32 + quad * 8];
                acc[fj] = __builtin_amdgcn_mfma_f32_16x16x32_bf16(av[ks], bx, acc[fj], 0, 0, 0);
            }
        #pragma unroll
        for (int r = 0; r < 4; ++r) {
            int e = w * 16 + quad * 4 + r;               // output dim
            float bias = bv[e];
            short4 pk;
            pk.x = bfbits(acc[0][r] + bias);
            pk.y = bfbits(acc[1][r] + bias);
            pk.z = bfbits(acc[2][r] + bias);
            pk.w = bfbits(acc[3][r] + bias);
            *(short4*)(Vt + ((size_t)((n * NHEAD + hh) * HDIM + e)) * SEQ
                       + s0loc + l15 * 4) = pk;
        }
    }
}

// ---------------- MFMA flash attention: 512 thr / 128 queries / split-K ---------
// launch_bounds(512,4): 128-reg cap (needs ~64; (512,8) forced spills, round 9).
__global__ __launch_bounds__(512, 4) void k_attn(const bf16* __restrict__ Qb,
                                                 const bf16* __restrict__ Kb,
                                                 const bf16* __restrict__ Vt,
                                                 const int* __restrict__ mask,
                                                 bf16* __restrict__ PoA,
                                                 bf16* __restrict__ PoB,
                                                 float* __restrict__ Mm,
                                                 float* __restrict__ Ll,
                                                 int ns_l2) {
    __shared__ __align__(16) short QPs[128 * 72];  // Q staging, then 8 P slabs
    __shared__ __align__(16) short Ks[64 * 72];
    __shared__ __align__(16) short Vs[80 * 72];    // 0-63 V^T perm; 64 ones; 65-79 zero
    int t = threadIdx.x, lane = t & 63, w = t >> 6;
    int l15 = lane & 15, quad = lane >> 4;
    int q0 = blockIdx.x * 128, hh = blockIdx.y;
    int z = blockIdx.z;
    int n = z >> ns_l2, sp = z & ((1 << ns_l2) - 1);
    size_t tokbase = (size_t)n * SEQ;
    size_t vbase = ((size_t)(n * NHEAD + hh) * HDIM) * SEQ;

    #pragma unroll
    for (int i = 0; i < 2; ++i) {
        int idx = t + 512 * i;
        int row = idx >> 3, q = idx & 7;
        *(uint4*)&QPs[row * 72 + q * 8] =
            *(const uint4*)(Qb + (tokbase + q0 + row) * DMODEL + hh * HDIM + q * 8);
    }
    for (int j = t; j < 16 * 72; j += 512) Vs[64 * 72 + j] = 0;
    if (t < 64) Vs[64 * 72 + t] = (short)0x3F80;   // bf16 1.0 ones-row (dim 64)
    __syncthreads();
    short8 aq[2];
    aq[0] = *(short8*)&QPs[(w * 16 + l15) * 72 + quad * 8];
    aq[1] = *(short8*)&QPs[(w * 16 + l15) * 72 + 32 + quad * 8];

    floatx4 accO[5];
    float mold[4];
    #pragma unroll
    for (int fn = 0; fn < 5; ++fn)
        #pragma unroll
        for (int r = 0; r < 4; ++r) accO[fn][r] = 0.f;
    #pragma unroll
    for (int r = 0; r < 4; ++r) mold[r] = -1.0e38f;

    int kquota = SEQ >> ns_l2;
    int kbeg = sp * kquota, kend = kbeg + kquota;
    for (int k0 = kbeg; k0 < kend; k0 += 64) {
        __syncthreads();
        {   // stage K (natural) and V^T (permuted global -> straight copy)
            int row = t >> 3, q = t & 7;
            *(uint4*)&Ks[row * 72 + q * 8] =
                *(const uint4*)(Kb + (tokbase + k0 + row) * DMODEL + hh * HDIM + q * 8);
            *(uint4*)&Vs[row * 72 + q * 8] =
                *(const uint4*)(Vt + vbase + (size_t)row * SEQ + k0 + q * 8);
        }
        __syncthreads();
        floatx4 accS[4];
        #pragma unroll
        for (int fj = 0; fj < 4; ++fj)
            #pragma unroll
            for (int r = 0; r < 4; ++r) accS[fj][r] = 0.f;
        #pragma unroll
        for (int ks = 0; ks < 2; ++ks)
            #pragma unroll
            for (int fj = 0; fj < 4; ++fj) {
                short8 bk = *(short8*)&Ks[(fj * 16 + l15) * 72 + ks * 32 + quad * 8];
                accS[fj] = __builtin_amdgcn_mfma_f32_16x16x32_bf16(aq[ks], bk, accS[fj], 0, 0, 0);
            }
        #pragma unroll
        for (int fj = 0; fj < 4; ++fj) {
            int mk = mask[n * SEQ + k0 + fj * 16 + l15];
            #pragma unroll
            for (int r = 0; r < 4; ++r)
                accS[fj][r] = mk ? accS[fj][r] : -1.0e9f;
        }
        float al[4];
        short* Ps = &QPs[w * 1152];
        #pragma unroll
        for (int r = 0; r < 4; ++r) {
            float mx = fmaxf(fmaxf(accS[0][r], accS[1][r]), fmaxf(accS[2][r], accS[3][r]));
            mx = fmaxf(mx, __shfl_xor(mx, 1, 64));
            mx = fmaxf(mx, __shfl_xor(mx, 2, 64));
            mx = fmaxf(mx, __shfl_xor(mx, 4, 64));
            mx = fmaxf(mx, __shfl_xor(mx, 8, 64));
            float mn = fmaxf(mold[r], mx);
            al[r] = exp2f(mold[r] - mn);
            mold[r] = mn;
            short4 pk;
            pk.x = bfbits(exp2f(accS[0][r] - mn));
            pk.y = bfbits(exp2f(accS[1][r] - mn));
            pk.z = bfbits(exp2f(accS[2][r] - mn));
            pk.w = bfbits(exp2f(accS[3][r] - mn));
            *(short4*)&Ps[(quad * 4 + r) * 72 + l15 * 4] = pk;   // b64 permuted store
        }
        #pragma unroll
        for (int fn = 0; fn < 5; ++fn)
            #pragma unroll
            for (int r = 0; r < 4; ++r) accO[fn][r] *= al[r];
        #pragma unroll
        for (int ks = 0; ks < 2; ++ks) {
            short8 ap = *(short8*)&Ps[l15 * 72 + ks * 32 + quad * 8];
            #pragma unroll
            for (int fn = 0; fn < 5; ++fn) {
                short8 bv = *(short8*)&Vs[(fn * 16 + l15) * 72 + ks * 32 + quad * 8];
                accO[fn] = __builtin_amdgcn_mfma_f32_16x16x32_bf16(ap, bv, accO[fn], 0, 0, 0);
            }
        }
    }
    bf16* Pob = (sp < 2) ? PoA : PoB;
    #pragma unroll
    for (int r = 0; r < 4; ++r) {
        float ls = __shfl(accO[4][r], lane & 48);
        int row = q0 + w * 16 + quad * 4 + r;
        size_t gtok = tokbase + row;
        bf16* dst = Pob + ((size_t)(sp & 1) * NS_TOK + gtok) * DMODEL + hh * HDIM;
        #pragma unroll
        for (int fn = 0; fn < 4; ++fn)
            dst[fn * 16 + l15] = f2bf(accO[fn][r]);
        if (l15 == 0) {
            Mm[((size_t)sp * NS_TOK + gtok) * NHEAD + hh] = mold[r];
            Ll[((size_t)sp * NS_TOK + gtok) * NHEAD + hh] = ls;
        }
    }
}

// ---------------- combine K-splits (2 or 4) ----------------
__global__ __launch_bounds__(256) void k_comb(const bf16* __restrict__ PoA,
    const bf16* __restrict__ PoB, const float* __restrict__ Mm,
    const float* __restrict__ Ll, bf16* __restrict__ Ab, int nsplit) {
    int tok = blockIdx.x * 4 + (threadIdx.x >> 6);
    int lane = threadIdx.x & 63;
    int hh = lane >> 3;
    float m = -1.0e38f;
    for (int s = 0; s < nsplit; ++s)
        m = fmaxf(m, Mm[((size_t)s * NS_TOK + tok) * NHEAD + hh]);
    float L = 0.f, wgt[4];
    for (int s = 0; s < nsplit; ++s) {
        wgt[s] = exp2f(Mm[((size_t)s * NS_TOK + tok) * NHEAD + hh] - m);
        L += Ll[((size_t)s * NS_TOK + tok) * NHEAD + hh] * wgt[s];
    }
    float inv = 1.f / L;
    float acc[8] = {0.f, 0.f, 0.f, 0.f, 0.f, 0.f, 0.f, 0.f};
    for (int s = 0; s < nsplit; ++s) {
        const bf16* basep = ((s < 2) ? PoA : PoB) +
                            ((size_t)(s & 1) * NS_TOK + tok) * DMODEL + lane * 8;
        uint4 u = *(const uint4*)basep;
        const unsigned int* p = (const unsigned int*)&u;
        #pragma unroll
        for (int j = 0; j < 4; ++j) {
            float2 f = bf2x2(p[j]);
            acc[j * 2]     += f.x * wgt[s];
            acc[j * 2 + 1] += f.y * wgt[s];
        }
    }
    bf16* dst = Ab + (size_t)tok * DMODEL + lane * 8;
    #pragma unroll
    for (int j = 0; j < 8; ++j) dst[j] = f2bf(acc[j] * inv);
}

// ---------------- fast MFMA GEMM (global_load_lds staging), direct epilogue -----
template<int MT, int NT, bool RELU>
__global__ __launch_bounds__(256) void k_gemm_f(const bf16* __restrict__ A,
    const bf16* __restrict__ W, const float* __restrict__ bias, int K, int N,
    const float* __restrict__ resid, float* __restrict__ outF, bf16* __restrict__ outB) {
    constexpr int FI = MT / 32;
    constexpr int FJ = NT / 32;
    __shared__ __align__(16) short As[MT * 32];
    __shared__ __align__(16) short Bs[NT * 32];
    int t = threadIdx.x, lane = t & 63, w = t >> 6;
    int m0 = blockIdx.x * MT, n0 = blockIdx.y * NT;
    int wrow = (w >> 1) * (MT / 2), wcol = (w & 1) * (NT / 2);
    int quad = lane >> 4, mrow = lane & 15;
    int lr = lane >> 2, lc = (lane & 3) * 8;
    floatx4 acc[FI][FJ];
    #pragma unroll
    for (int fi = 0; fi < FI; ++fi)
        #pragma unroll
        for (int fj = 0; fj < FJ; ++fj)
            #pragma unroll
            for (int r = 0; r < 4; ++r) acc[fi][fj][r] = 0.f;

    for (int k0 = 0; k0 < K; k0 += 32) {
        __syncthreads();
        #pragma unroll
        for (int i = 0; i < MT / 64; ++i) {
            int rbase = (i * 4 + w) * 16;
            gl2lds16(A + (size_t)(m0 + rbase + lr) * K + k0 + lc, &As[rbase * 32]);
        }
        #pragma unroll
        for (int i = 0; i < NT / 64; ++i) {
            int rbase = (i * 4 + w) * 16;
            gl2lds16(W + (size_t)(n0 + rbase + lr) * K + k0 + lc, &Bs[rbase * 32]);
        }
        __syncthreads();
        short8 af[FI], bfr[FJ];
        #pragma unroll
        for (int fi = 0; fi < FI; ++fi)
            af[fi] = *(short8*)&As[(wrow + fi * 16 + mrow) * 32 + quad * 8];
        #pragma unroll
        for (int fj = 0; fj < FJ; ++fj)
            bfr[fj] = *(short8*)&Bs[(wcol + fj * 16 + mrow) * 32 + quad * 8];
        #pragma unroll
        for (int fi = 0; fi < FI; ++fi)
            #pragma unroll
            for (int fj = 0; fj < FJ; ++fj)
                acc[fi][fj] = __builtin_amdgcn_mfma_f32_16x16x32_bf16(
                    af[fi], bfr[fj], acc[fi][fj], 0, 0, 0);
    }
    #pragma unroll
    for (int fi = 0; fi < FI; ++fi)
        #pragma unroll
        for (int fj = 0; fj < FJ; ++fj) {
            int col = n0 + wcol + fj * 16 + mrow;
            float bv = bias[col];
            #pragma unroll
            for (int r = 0; r < 4; ++r) {
                int row = m0 + wrow + fi * 16 + quad * 4 + r;
                float v = acc[fi][fj][r] + bv;
                if (RELU) {
                    outB[(size_t)row * N + col] = f2bf(fmaxf(v, 0.f));
                } else {
                    outF[(size_t)row * N + col] = v + resid[(size_t)row * N + col];
                }
            }
        }
}

// ---------------- fast MFMA GEMM, split-K(2), bf16 partials ----------------
template<int MT, int NT>
__global__ __launch_bounds__(256) void k_gemm_sk(const bf16* __restrict__ A,
    const bf16* __restrict__ W, int K, int N,
    bf16* __restrict__ out0, bf16* __restrict__ out1) {
    constexpr int FI = MT / 32;
    constexpr int FJ = NT / 32;
    __shared__ __align__(16) short As[MT * 32];
    __shared__ __align__(16) short Bs[NT * 32];
    int t = threadIdx.x, lane = t & 63, w = t >> 6;
    int m0 = blockIdx.x * MT, n0 = blockIdx.y * NT;
    int wrow = (w >> 1) * (MT / 2), wcol = (w & 1) * (NT / 2);
    int quad = lane >> 4, mrow = lane & 15;
    int lr = lane >> 2, lc = (lane & 3) * 8;
    floatx4 acc[FI][FJ];
    #pragma unroll
    for (int fi = 0; fi < FI; ++fi)
        #pragma unroll
        for (int fj = 0; fj < FJ; ++fj)
            #pragma unroll
            for (int r = 0; r < 4; ++r) acc[fi][fj][r] = 0.f;

    int kh = K >> 1;
    int kbeg = blockIdx.z * kh;
    for (int k0 = kbeg; k0 < kbeg + kh; k0 += 32) {
        __syncthreads();
        #pragma unroll
        for (int i = 0; i < MT / 64; ++i) {
            int rbase = (i * 4 + w) * 16;
            gl2lds16(A + (size_t)(m0 + rbase + lr) * K + k0 + lc, &As[rbase * 32]);
        }
        #pragma unroll
        for (int i = 0; i < NT / 64; ++i) {
            int rbase = (i * 4 + w) * 16;
            gl2lds16(W + (size_t)(n0 + rbase + lr) * K + k0 + lc, &Bs[rbase * 32]);
        }
        __syncthreads();
        short8 af[FI], bfr[FJ];
        #pragma unroll
        for (int fi = 0; fi < FI; ++fi)
            af[fi] = *(short8*)&As[(wrow + fi * 16 + mrow) * 32 + quad * 8];
        #pragma unroll
        for (int fj = 0; fj < FJ; ++fj)
            bfr[fj] = *(short8*)&Bs[(wcol + fj * 16 + mrow) * 32 + quad * 8];
        #pragma unroll
        for (int fi = 0; fi < FI; ++fi)
            #pragma unroll
            for (int fj = 0; fj < FJ; ++fj)
                acc[fi][fj] = __builtin_amdgcn_mfma_f32_16x16x32_bf16(
                    af[fi], bfr[fj], acc[fi][fj], 0, 0, 0);
    }
    bf16* out = blockIdx.z ? out1 : out0;
    #pragma unroll
    for (int fi = 0; fi < FI; ++fi)
        #pragma unroll
        for (int fj = 0; fj < FJ; ++fj) {
            int col = n0 + wcol + fj * 16 + mrow;
            #pragma unroll
            for (int r = 0; r < 4; ++r) {
                int row = m0 + wrow + fi * 16 + quad * 4 + r;
                out[(size_t)row * N + col] = f2bf(acc[fi][fj][r]);
            }
        }
}

// ---------------- slow fp32-weight GEMM (tier-0 fallback) ----------------
template<int MT, bool RELU>
__global__ __launch_bounds__(256) void k_gemm(const bf16* __restrict__ A,
    const float* __restrict__ Wf, const float* __restrict__ bias, int K, int N,
    const float* __restrict__ resid, float* __restrict__ outF, bf16* __restrict__ outB) {
    constexpr int FI = 4;
    constexpr int FJ = (MT == 128) ? 4 : 2;
    __shared__ short As[MT * 40];
    __shared__ short Bs[128 * 40];
    int t = threadIdx.x, lane = t & 63, w = t >> 6;
    int m0 = blockIdx.x * MT, n0 = blockIdx.y * 128;
    int wrow = (MT == 128) ? (w >> 1) * 64 : 0;
    int wcol = (MT == 128) ? (w & 1) * 64 : w * 32;
    int quad = lane >> 4, mrow = lane & 15;
    floatx4 acc[FI][FJ];
    #pragma unroll
    for (int fi = 0; fi < FI; ++fi)
        #pragma unroll
        for (int fj = 0; fj < FJ; ++fj)
            #pragma unroll
            for (int r = 0; r < 4; ++r) acc[fi][fj][r] = 0.f;
    for (int k0 = 0; k0 < K; k0 += 32) {
        __syncthreads();
        #pragma unroll
        for (int i = 0; i < MT / 64; ++i) {
            int idx = t + i * 256;
            int row = idx >> 2, q = idx & 3;
            uint4 u = *(const uint4*)(A + (size_t)(m0 + row) * K + k0 + q * 8);
            *(uint4*)&As[row * 40 + q * 8] = u;
        }
        #pragma unroll
        for (int i = 0; i < 2; ++i) {
            int idx = t + i * 256;
            int row = idx >> 2, q = idx & 3;
            const float* src = Wf + (size_t)(n0 + row) * K + k0 + q * 8;
            float4 f0 = *(const float4*)src;
            float4 f1 = *(const float4*)(src + 4);
            short8 sv;
            sv[0] = bfbits(f0.x); sv[1] = bfbits(f0.y);
            sv[2] = bfbits(f0.z); sv[3] = bfbits(f0.w);
            sv[4] = bfbits(f1.x); sv[5] = bfbits(f1.y);
            sv[6] = bfbits(f1.z); sv[7] = bfbits(f1.w);
            *(short8*)&Bs[row * 40 + q * 8] = sv;
        }
        __syncthreads();
        short8 af[FI], bfr[FJ];
        #pragma unroll
        for (int fi = 0; fi < FI; ++fi)
            af[fi] = *(short8*)&As[(wrow + fi * 16 + mrow) * 40 + quad * 8];
        #pragma unroll
        for (int fj = 0; fj < FJ; ++fj)
            bfr[fj] = *(short8*)&Bs[(wcol + fj * 16 + mrow) * 40 + quad * 8];
        #pragma unroll
        for (int fi = 0; fi < FI; ++fi)
            #pragma unroll
            for (int fj = 0; fj < FJ; ++fj)
                acc[fi][fj] = __builtin_amdgcn_mfma_f32_16x16x32_bf16(
                    af[fi], bfr[fj], acc[fi][fj], 0, 0, 0);
    }
    #pragma unroll
    for (int fi = 0; fi < FI; ++fi)
        #pragma unroll
        for (int fj = 0; fj < FJ; ++fj) {
            int col = n0 + wcol + fj * 16 + mrow;
            float bv = bias[col];
            #pragma unroll
            for (int r = 0; r < 4; ++r) {
                int row = m0 + wrow + fi * 16 + quad * 4 + r;
                float v = acc[fi][fj][r] + bv;
                if (RELU) {
                    outB[(size_t)row * N + col] = f2bf(fmaxf(v, 0.f));
                } else {
                    outF[(size_t)row * N + col] = v + resid[(size_t)row * N + col];
                }
            }
        }
}

// ---------------- LayerNorm (plain, tiers 0/1) ----------------
__global__ __launch_bounds__(256) void k_ln(const float* __restrict__ P,
    const float* __restrict__ g, const float* __restrict__ b,
    float* __restrict__ outF, bf16* __restrict__ outB) {
    int row = blockIdx.x * 4 + (threadIdx.x >> 6);
    int lane = threadIdx.x & 63;
    const float* p = P + (size_t)row * DMODEL + lane * 8;
    float4 a = *(const float4*)p;
    float4 c = *(const float4*)(p + 4);
    float s = a.x + a.y + a.z + a.w + c.x + c.y + c.z + c.w;
    #pragma unroll
    for (int off = 32; off > 0; off >>= 1) s += __shfl_xor(s, off, 64);
    float mean = s * (1.f / DMODEL);
    float d[8] = {a.x - mean, a.y - mean, a.z - mean, a.w - mean,
                  c.x - mean, c.y - mean, c.z - mean, c.w - mean};
    float vs = 0.f;
    #pragma unroll
    for (int j = 0; j < 8; ++j) vs += d[j] * d[j];
    #pragma unroll
    for (int off = 32; off > 0; off >>= 1) vs += __shfl_xor(vs, off, 64);
    float rstd = rsqrtf(vs * (1.f / DMODEL) + 1e-5f);
    float4 g0 = *(const float4*)(g + lane * 8);
    float4 g1 = *(const float4*)(g + lane * 8 + 4);
    float4 b0 = *(const float4*)(b + lane * 8);
    float4 b1 = *(const float4*)(b + lane * 8 + 4);
    float o[8] = {d[0] * rstd * g0.x + b0.x, d[1] * rstd * g0.y + b0.y,
                  d[2] * rstd * g0.z + b0.z, d[3] * rstd * g0.w + b0.w,
                  d[4] * rstd * g1.x + b1.x, d[5] * rstd * g1.y + b1.y,
                  d[6] * rstd * g1.z + b1.z, d[7] * rstd * g1.w + b1.w};
    float* of = outF + (size_t)row * DMODEL + lane * 8;
    *(float4*)of       = make_float4(o[0], o[1], o[2], o[3]);
    *(float4*)(of + 4) = make_float4(o[4], o[5], o[6], o[7]);
    if (outB) {
        bf16* ob = outB + (size_t)row * DMODEL + lane * 8;
        #pragma unroll
        for (int j = 0; j < 8; ++j) ob[j] = f2bf(o[j]);
    }
}

// ---------------- fused: combine bf16 split-K partials + bias + resid + LN ------
__global__ __launch_bounds__(256) void k_lncomb(const bf16* __restrict__ pp0,
    const bf16* __restrict__ pp1, const float* __restrict__ bias,
    const float* __restrict__ resid, const float* __restrict__ g,
    const float* __restrict__ b, float* __restrict__ outF, bf16* __restrict__ outB) {
    int row = blockIdx.x * 4 + (threadIdx.x >> 6);
    int lane = threadIdx.x & 63;
    size_t idx = (size_t)row * DMODEL + lane * 8;
    uint4 u0 = *(const uint4*)(pp0 + idx);
    uint4 u1 = *(const uint4*)(pp1 + idx);
    float4 r0 = *(const float4*)(resid + idx), r1 = *(const float4*)(resid + idx + 4);
    float4 q0 = *(const float4*)(bias + lane * 8), q1 = *(const float4*)(bias + lane * 8 + 4);
    const unsigned int* a0 = (const unsigned int*)&u0;
    const unsigned int* a1 = (const unsigned int*)&u1;
    float v[8];
    #pragma unroll
    for (int j = 0; j < 4; ++j) {
        float2 f0 = bf2x2(a0[j]), f1 = bf2x2(a1[j]);
        v[j * 2]     = f0.x + f1.x;
        v[j * 2 + 1] = f0.y + f1.y;
    }
    v[0] += r0.x + q0.x; v[1] += r0.y + q0.y; v[2] += r0.z + q0.z; v[3] += r0.w + q0.w;
    v[4] += r1.x + q1.x; v[5] += r1.y + q1.y; v[6] += r1.z + q1.z; v[7] += r1.w + q1.w;
    float s = 0.f;
    #pragma unroll
    for (int j = 0; j < 8; ++j) s += v[j];
    #pragma unroll
    for (int off = 32; off > 0; off >>= 1) s += __shfl_xor(s, off, 64);
    float mean = s * (1.f / DMODEL);
    float vs = 0.f;
    #pragma unroll
    for (int j = 0; j < 8; ++j) { v[j] -= mean; vs += v[j] * v[j]; }
    #pragma unroll
    for (int off = 32; off > 0; off >>= 1) vs += __shfl_xor(vs, off, 64);
    float rstd = rsqrtf(vs * (1.f / DMODEL) + 1e-5f);
    float4 g0 = *(const float4*)(g + lane * 8);
    float4 g1 = *(const float4*)(g + lane * 8 + 4);
    float4 b0 = *(const float4*)(b + lane * 8);
    float4 b1 = *(const float4*)(b + lane * 8 + 4);
    float o[8] = {v[0] * rstd * g0.x + b0.x, v[1] * rstd * g0.y + b0.y,
                  v[2] * rstd * g0.z + b0.z, v[3] * rstd * g0.w + b0.w,
                  v[4] * rstd * g1.x + b1.x, v[5] * rstd * g1.y + b1.y,
                  v[6] * rstd * g1.z + b1.z, v[7] * rstd * g1.w + b1.w};
    float* of = outF + idx;
    *(float4*)of       = make_float4(o[0], o[1], o[2], o[3]);
    *(float4*)(of + 4) = make_float4(o[4], o[5], o[6], o[7]);
    if (outB) {
        bf16* ob = outB + idx;
        #pragma unroll
        for (int j = 0; j < 8; ++j) ob[j] = f2bf(o[j]);
    }
}

extern "C" void kernel_launch(void* const* d_in, const int* in_sizes, int n_in,
                              void* d_out, int out_size, void* d_ws, size_t ws_size,
                              hipStream_t stream) {
    const int*   src  = (const int*)d_in[0];
    const int*   mask = (const int*)d_in[1];
    const float* emb  = (const float*)d_in[2];
    const float* Wq   = (const float*)d_in[3];
    const float* bq   = (const float*)d_in[4];
    const float* Wk   = (const float*)d_in[5];
    const float* bk   = (const float*)d_in[6];
    const float* Wv   = (const float*)d_in[7];
    const float* bv   = (const float*)d_in[8];
    const float* Wo   = (const float*)d_in[9];
    const float* bo   = (const float*)d_in[10];
    const float* W1   = (const float*)d_in[11];
    const float* b1   = (const float*)d_in[12];
    const float* W2   = (const float*)d_in[13];
    const float* b2   = (const float*)d_in[14];
    const float* ln1g = (const float*)d_in[15];
    const float* ln1b = (const float*)d_in[16];
    const float* ln2g = (const float*)d_in[17];
    const float* ln2b = (const float*)d_in[18];

    char* base = (char*)d_ws;
    float* h   = (float*)base;                       // 8,388,608
    float* hbf = (float*)(base + 8388608);           // 4,194,304 (hb + Mm/Ll alias)
    bf16*  hb  = (bf16*)hbf;
    float* Mm  = hbf;
    float* Ll  = hbf + 4 * NS_TOK * NHEAD;
    char*  P0r = base + 12582912;                    // 8,388,608
    bf16*  Qb  = (bf16*)(base + 20971520);           // 4 x 4,194,304
    bf16*  Kb  = (bf16*)(base + 25165824);
    bf16*  Vt  = (bf16*)(base + 29360128);           // permuted-key V [dim][key']
    bf16*  Ab  = (bf16*)(base + 33554432);
    bf16*  F1b = Qb;                                  // aliases Qb..Ab
    bf16*  Wob = (bf16*)(base + 37748736);           // 3,145,728
    bf16*  W1b = (bf16*)(base + 40894464);           // 12,582,912
    bf16*  W2b = (bf16*)(base + 53477376);           // 12,582,912
    char*  P1r = base + 66060288;                    // 8,388,608 -> 74,448,896
    int tier = (ws_size >= 74448896ull) ? 2 : ((ws_size >= 66060288ull) ? 1 : 0);

    if (tier >= 1) {
        k_conv<<<(6 * DMODEL * DMODEL) / 2048, 256, 0, stream>>>(Wo, Wob, 6 * DMODEL * DMODEL);
        k_conv<<<(6 * FFDIM * DMODEL) / 2048, 256, 0, stream>>>(W1, W1b, 6 * FFDIM * DMODEL);
        k_conv<<<(6 * FFDIM * DMODEL) / 2048, 256, 0, stream>>>(W2, W2b, 6 * FFDIM * DMODEL);
    }
    k_embed<<<NS_TOK, 256, 0, stream>>>(src, emb, h, hb);

    int ns_l2 = (tier == 2) ? 2 : 1;
    int nsplit = 1 << ns_l2;
    bf16* PoA = (bf16*)P0r;
    bf16* PoB = (tier == 2) ? (bf16*)P1r : (bf16*)P0r;
    bf16* Pp0 = (bf16*)P0r;
    bf16* Pp1 = (tier == 2) ? (bf16*)P1r : (bf16*)P0r;

    for (int l = 0; l < 6; ++l) {
        k_qkv<<<dim3(NS_TOK / 64, NHEAD), 256, 0, stream>>>(hb,
            Wq + (size_t)l * HDIM * HDIM, bq + l * HDIM,
            Wk + (size_t)l * HDIM * HDIM, bk + l * HDIM,
            Wv + (size_t)l * HDIM * HDIM, bv + l * HDIM,
            Qb, Kb, Vt);
        k_attn<<<dim3(SEQ / 128, NHEAD, NB * nsplit), 512, 0, stream>>>(
            Qb, Kb, Vt, mask, PoA, PoB, Mm, Ll, ns_l2);
        k_comb<<<NS_TOK / 4, 256, 0, stream>>>(PoA, PoB, Mm, Ll, Ab, nsplit);

        float* lnout = (l == 5) ? (float*)d_out : h;
        bf16* lnoutB = (l == 5) ? nullptr : hb;

        if (tier == 2) {
            k_gemm_sk<64, 128><<<dim3(NS_TOK / 64, DMODEL / 128, 2), 256, 0, stream>>>(
                Ab, Wob + (size_t)l * DMODEL * DMODEL, DMODEL, DMODEL, Pp0, Pp1);
            k_lncomb<<<NS_TOK / 4, 256, 0, stream>>>(Pp0, Pp1, bo + l * DMODEL, h,
                ln1g + l * DMODEL, ln1b + l * DMODEL, h, hb);
            k_gemm_f<128, 128, true><<<dim3(NS_TOK / 128, FFDIM / 128), 256, 0, stream>>>(
                hb, W1b + (size_t)l * FFDIM * DMODEL, b1 + l * FFDIM,
                DMODEL, FFDIM, nullptr, nullptr, F1b);
            k_gemm_sk<64, 128><<<dim3(NS_TOK / 64, DMODEL / 128, 2), 256, 0, stream>>>(
                F1b, W2b + (size_t)l * DMODEL * FFDIM, FFDIM, DMODEL, Pp0, Pp1);
            k_lncomb<<<NS_TOK / 4, 256, 0, stream>>>(Pp0, Pp1, b2 + l * DMODEL, h,
                ln2g + l * DMODEL, ln2b + l * DMODEL, lnout, lnoutB);
        } else if (tier == 1) {
            k_gemm_f<64, 128, false><<<dim3(NS_TOK / 64, DMODEL / 128), 256, 0, stream>>>(
                Ab, Wob + (size_t)l * DMODEL * DMODEL, bo + l * DMODEL,
                DMODEL, DMODEL, h, (float*)P0r, nullptr);
            k_ln<<<NS_TOK / 4, 256, 0, stream>>>((float*)P0r, ln1g + l * DMODEL, ln1b + l * DMODEL, h, hb);
            k_gemm_f<128, 128, true><<<dim3(NS_TOK / 128, FFDIM / 128), 256, 0, stream>>>(
                hb, W1b + (size_t)l * FFDIM * DMODEL, b1 + l * FFDIM,
                DMODEL, FFDIM, nullptr, nullptr, F1b);
            k_gemm_f<64, 128, false><<<dim3(NS_TOK / 64, DMODEL / 128), 256, 0, stream>>>(
                F1b, W2b + (size_t)l * DMODEL * FFDIM, b2 + l * DMODEL,
                FFDIM, DMODEL, h, (float*)P0r, nullptr);
            k_ln<<<NS_TOK / 4, 256, 0, stream>>>((float*)P0r, ln2g + l * DMODEL, ln2b + l * DMODEL, lnout, lnoutB);
        } else {
            k_gemm<64, false><<<dim3(NS_TOK / 64, DMODEL / 128), 256, 0, stream>>>(
                Ab, Wo + (size_t)l * DMODEL * DMODEL, bo + l * DMODEL,
                DMODEL, DMODEL, h, (float*)P0r, nullptr);
            k_ln<<<NS_TOK / 4, 256, 0, stream>>>((float*)P0r, ln1g + l * DMODEL, ln1b + l * DMODEL, h, hb);
            k_gemm<128, true><<<dim3(NS_TOK / 128, FFDIM / 128), 256, 0, stream>>>(
                hb, W1 + (size_t)l * FFDIM * DMODEL, b1 + l * FFDIM,
                DMODEL, FFDIM, nullptr, nullptr, F1b);
            k_gemm<64, false><<<dim3(NS_TOK / 64, DMODEL / 128), 256, 0, stream>>>(
                F1b, W2 + (size_t)l * DMODEL * FFDIM, b2 + l * DMODEL,
                FFDIM, DMODEL, h, (float*)P0r, nullptr);
            k_ln<<<NS_TOK / 4, 256, 0, stream>>>((float*)P0r, ln2g + l * DMODEL, ln2b + l * DMODEL, lnout, lnoutB);
        }
    }
}